// Round 2
// baseline (368.532 us; speedup 1.0000x reference)
//
#include <hip/hip_runtime.h>
#include <hip/hip_bf16.h>

#define NREL 8
#define CH   64   // IN_CH == HID_CH == 64

// ---------------------------------------------------------------------------
// Kernel 1: xw[r][n][h] = sum_i x[n][i] * W[r][i][h]
// Block: 256 threads, one (64-node tile, relation) pair per block.
// LDS: x tile transposed (xT[i][n]) + W[r] (w[i][h]), 16 KB each.
// Each thread computes a 4x4 (node x h) register tile.
// ---------------------------------------------------------------------------
__global__ __launch_bounds__(256) void rgcn_xw_kernel(
    const float* __restrict__ x, const float* __restrict__ W,
    float* __restrict__ xw, int nN)
{
    __shared__ float xT[64 * 64];   // [i][n]
    __shared__ float wb[64 * 64];   // [i][h]

    const int t      = threadIdx.x;
    const int tile   = blockIdx.x;
    const int r      = blockIdx.y;
    const int n_base = tile * 64;

    // Load W[r]: 4096 floats = 256 threads x 4 float4s, layout [i][h].
    {
        const float* wsrc = W + ((size_t)r << 12);
        #pragma unroll
        for (int j = 0; j < 4; ++j) {
            const int off = (t << 2) + (j << 10);
            *(float4*)(wb + off) = *(const float4*)(wsrc + off);
        }
    }

    // Load x tile transposed. Thread t: node lane n_l = t&63, i-chunk (t>>6)*16.
    {
        const int n_l = t & 63;
        const int i0  = (t >> 6) << 4;
        const int n   = n_base + n_l;
        if (n < nN) {
            const float* xp = x + (size_t)n * CH + i0;
            #pragma unroll
            for (int j = 0; j < 4; ++j) {
                const float4 v = *(const float4*)(xp + j * 4);
                xT[(i0 + j * 4 + 0) * 64 + n_l] = v.x;
                xT[(i0 + j * 4 + 1) * 64 + n_l] = v.y;
                xT[(i0 + j * 4 + 2) * 64 + n_l] = v.z;
                xT[(i0 + j * 4 + 3) * 64 + n_l] = v.w;
            }
        } else {
            #pragma unroll
            for (int j = 0; j < 16; ++j) xT[(i0 + j) * 64 + n_l] = 0.f;
        }
    }
    __syncthreads();

    const int tn = t >> 4;   // 0..15 -> node quad
    const int th = t & 15;   // 0..15 -> h quad

    float acc[4][4];
    #pragma unroll
    for (int a = 0; a < 4; ++a)
        #pragma unroll
        for (int b = 0; b < 4; ++b) acc[a][b] = 0.f;

    #pragma unroll
    for (int i = 0; i < 64; ++i) {
        const float4 av = *(const float4*)(xT + i * 64 + (tn << 2));
        const float4 bv = *(const float4*)(wb + i * 64 + (th << 2));
        acc[0][0] += av.x * bv.x; acc[0][1] += av.x * bv.y;
        acc[0][2] += av.x * bv.z; acc[0][3] += av.x * bv.w;
        acc[1][0] += av.y * bv.x; acc[1][1] += av.y * bv.y;
        acc[1][2] += av.y * bv.z; acc[1][3] += av.y * bv.w;
        acc[2][0] += av.z * bv.x; acc[2][1] += av.z * bv.y;
        acc[2][2] += av.z * bv.z; acc[2][3] += av.z * bv.w;
        acc[3][0] += av.w * bv.x; acc[3][1] += av.w * bv.y;
        acc[3][2] += av.w * bv.z; acc[3][3] += av.w * bv.w;
    }

    #pragma unroll
    for (int dn = 0; dn < 4; ++dn) {
        const int n = n_base + (tn << 2) + dn;
        if (n < nN) {
            float4 o;
            o.x = acc[dn][0]; o.y = acc[dn][1]; o.z = acc[dn][2]; o.w = acc[dn][3];
            *(float4*)(xw + ((size_t)r * nN + n) * CH + (th << 2)) = o;
        }
    }
}

// ---------------------------------------------------------------------------
// Kernel 2: per-edge scatter. One wave per edge iteration; lane = channel.
// Gather xw[rel, src, lane] and atomicAdd into out[dst, lane].
// ---------------------------------------------------------------------------
__global__ __launch_bounds__(256) void rgcn_scatter_kernel(
    const float* __restrict__ xw, const int* __restrict__ ei,
    const int* __restrict__ rel, float* __restrict__ out,
    int nE, int nN, int nWaves)
{
    const int w    = (int)((blockIdx.x * 256u + threadIdx.x) >> 6);
    const int lane = threadIdx.x & 63;

    for (int e = w; e < nE; e += nWaves) {
        const int src = ei[e];
        const int dst = ei[nE + e];
        const int r   = rel[e];
        const float v = xw[((size_t)r * nN + src) * CH + lane];
        atomicAdd(out + (size_t)dst * CH + lane, v);
    }
}

// ---------------------------------------------------------------------------
// Fallback (ws too small): compute x[src] @ W[rel] per edge directly.
// ---------------------------------------------------------------------------
__global__ __launch_bounds__(256) void rgcn_direct_kernel(
    const float* __restrict__ x, const float* __restrict__ W,
    const int* __restrict__ ei, const int* __restrict__ rel,
    float* __restrict__ out, int nE, int nWaves)
{
    const int w    = (int)((blockIdx.x * 256u + threadIdx.x) >> 6);
    const int lane = threadIdx.x & 63;

    for (int e = w; e < nE; e += nWaves) {
        const int src = ei[e];
        const int dst = ei[nE + e];
        const int r   = rel[e];
        const float* xrow = x + (size_t)src * CH;
        const float* wcol = W + ((size_t)r << 12) + lane;
        float acc = 0.f;
        #pragma unroll
        for (int i = 0; i < CH; ++i) acc += xrow[i] * wcol[i * CH];
        atomicAdd(out + (size_t)dst * CH + lane, acc);
    }
}

extern "C" void kernel_launch(void* const* d_in, const int* in_sizes, int n_in,
                              void* d_out, int out_size, void* d_ws, size_t ws_size,
                              hipStream_t stream) {
    const float* x   = (const float*)d_in[0];
    const float* W   = (const float*)d_in[1];
    const int*   ei  = (const int*)d_in[2];
    const int*   rel = (const int*)d_in[3];
    float*       out = (float*)d_out;

    const int nN = in_sizes[0] / CH;   // 50000
    const int nE = in_sizes[3];        // 1000000

    // Harness poisons d_out once and never re-zeroes: clear it every call.
    hipMemsetAsync(out, 0, (size_t)out_size * sizeof(float), stream);

    const size_t need = (size_t)NREL * (size_t)nN * CH * sizeof(float);
    if (ws_size >= need) {
        float* xw = (float*)d_ws;
        dim3 grid((nN + 63) / 64, NREL);
        rgcn_xw_kernel<<<grid, 256, 0, stream>>>(x, W, xw, nN);

        const int blocks = 2048;
        const int nWaves = blocks * (256 / 64);
        rgcn_scatter_kernel<<<blocks, 256, 0, stream>>>(xw, ei, rel, out, nE, nN, nWaves);
    } else {
        const int blocks = 2048;
        const int nWaves = blocks * (256 / 64);
        rgcn_direct_kernel<<<blocks, 256, 0, stream>>>(x, W, ei, rel, out, nE, nWaves);
    }
}